// Round 17
// baseline (50.230 us; speedup 1.0000x reference)
//
#include <hip/hip_runtime.h>
#include <hip/hip_bf16.h>

#define TT 2048
#define HH 1024
#define NTAGS 74
#define NPAD 80
#define CHK 128           // K elements per chunk
#define NCH (HH / CHK)    // 8 chunks
#define MROWS 64          // rows per block
#define THREADS 256
#define NXCD 8
// dynamic LDS: A[2] 16KB @0,@16384; W[2] 20KB @32768,@53248 -> 73728 B total
#define ABUF(b) ((b) * 16384)
#define WBUF(b) (32768 + (b) * 20480)
#define LDS_BYTES 73728

typedef __bf16 bf16x8 __attribute__((ext_vector_type(8)));
typedef float f32x4 __attribute__((ext_vector_type(4)));

// Transpose + convert W_out [1024][74] f32 -> Wt [80][1024] bf16 (pad cols 74..79 = 0)
__global__ __launch_bounds__(256) void prep_w_kernel(const float* __restrict__ W,
                                                     __bf16* __restrict__ Wt) {
    __shared__ float tile[64][80];
    const int k0 = blockIdx.x * 64;
    const int tid = threadIdx.x;
    for (int i = tid; i < 64 * NTAGS; i += 256) {
        int k = i / NTAGS, n = i - k * NTAGS;
        tile[k][n] = W[(k0 + k) * NTAGS + n];
    }
    __syncthreads();
    for (int i = tid; i < NPAD * 64; i += 256) {
        int n = i >> 6, kk = i & 63;
        float v = (n < NTAGS) ? tile[kk][n] : 0.0f;
        Wt[n * HH + k0 + kk] = (__bf16)v;
    }
}

// R17 = R12 + ONE axis: phase granularity. CHK 64->128, NCH 16->8, dynamic
// LDS 72KB (A 2x16KB dbuf, W 2x20KB dbuf; 2 blocks/CU = 144KB <= 160KB).
// Phase count is the only knob never varied downward: 32-phase variants were
// worse (R9 37.9, R13 47.2), 16-phase is the 35us floor -> test 8 phases.
// Per chunk per thread: 8 char f4 + 8 word f4 + 5 W bf16x8 held in regs.
// Everything else (row map, swizzle family, XCD swizzle, early-exit,
// pipeline order, epilogue) identical to R12/R15.
__global__ __launch_bounds__(256, 2) void slu_main(const float* __restrict__ out_char,
                                                   const float* __restrict__ out_word,
                                                   const int* __restrict__ word_idx,
                                                   const int* __restrict__ is_head,
                                                   const int* __restrict__ valid_mask,
                                                   const __bf16* __restrict__ Wt,
                                                   const float* __restrict__ b_out,
                                                   float* __restrict__ out) {
    extern __shared__ __align__(16) char smem[];
    const int tid = threadIdx.x;
    const int wv = tid >> 6;
    const int lane = tid & 63;
    const int l15 = lane & 15;
    const int kgrp = lane >> 4;

    // ---- XCD-aware bijective swizzle (512 blocks = 8 XCDs x 64 chunks) ----
    const int bid = blockIdx.x;
    const int rb = (bid & (NXCD - 1)) * (512 / NXCD) + (bid >> 3);
    const int rowbase = rb * MROWS;

    // ---- A staging: thread covers row rloc=tid>>2, quarter q=tid&3 (32 f32/chunk) ----
    const int rloc = tid >> 2;
    const int q = tid & 3;
    const int r = rowbase + rloc;
    const int bq = r >> 11;  // T = 2048
    const int widx = word_idx[r];
    const int val = valid_mask[r];

    // ---- early-exit: fully-invalid block writes bias rows and returns ----
    if (!__syncthreads_or(val)) {
        for (int i = tid; i < MROWS * NTAGS; i += THREADS) {
            const int rr = i / NTAGS, cc2 = i - rr * NTAGS;
            out[(size_t)(rowbase + rr) * NTAGS + cc2] = b_out[cc2];
        }
        return;
    }

    const float rt = is_head[r] ? 0.88f : 0.70f;
    const float rate = val ? rt : 0.0f;
    const float crate = val ? (1.0f - rt) : 0.0f;
    const float* cptr = out_char + (size_t)r * HH + q * 32;
    const float* wptr = out_word + ((size_t)bq * TT + widx) * HH + q * 32;
    // LDS A: row stride 256 B (128 bf16); thread writes 64 B at q*64, 4x16B pieces
    const int asw = (rloc & 7) << 4;
    int awr[4];
#pragma unroll
    for (int i = 0; i < 4; ++i) awr[i] = (rloc * 256 + q * 64 + i * 16) ^ asw;

    // ---- W staging: 1280 16B-units/chunk = 5/thread: u = tid + 256p ----
    const __bf16* wsrc[5];
    int wwr[5];
#pragma unroll
    for (int p = 0; p < 5; ++p) {
        const int u = tid + 256 * p;
        const int n = u >> 4, sub = u & 15;
        wsrc[p] = Wt + (size_t)n * HH + sub * 8;
        wwr[p] = (n * 256 + sub * 16) ^ ((n & 7) << 4);
    }

    // ---- fragment read offsets (4 sub-k steps per chunk) ----
    const int fsw = (l15 & 7) << 4;
    const int arow = wv * 16 + l15;
    int aoff[4], woff[4][5];
#pragma unroll
    for (int s = 0; s < 4; ++s) {
        aoff[s] = (arow * 256 + s * 64 + kgrp * 16) ^ fsw;
#pragma unroll
        for (int nt = 0; nt < 5; ++nt)
            woff[s][nt] = ((nt * 16 + l15) * 256 + s * 64 + kgrp * 16) ^ fsw;
    }

    f32x4 acc[5];
#pragma unroll
    for (int nt = 0; nt < 5; ++nt) acc[nt] = (f32x4){0.f, 0.f, 0.f, 0.f};

    float4 cc[8], uc[8];    // held A loads (chunk ch+2)
    bf16x8 wreg[5];

    // commit: blend 8+8 f4 -> 4 bf16x8 -> LDS
#define COMMIT_A(base)                                                       \
    {                                                                        \
        _Pragma("unroll") for (int i2 = 0; i2 < 4; ++i2) {                   \
            bf16x8 f_;                                                       \
            if (val) {                                                       \
                const float4 ca_ = cc[2 * i2], cb_ = cc[2 * i2 + 1];         \
                const float4 wa_ = uc[2 * i2], wb_ = uc[2 * i2 + 1];         \
                f_[0] = (__bf16)(wa_.x * rate + ca_.x * crate);              \
                f_[1] = (__bf16)(wa_.y * rate + ca_.y * crate);              \
                f_[2] = (__bf16)(wa_.z * rate + ca_.z * crate);              \
                f_[3] = (__bf16)(wa_.w * rate + ca_.w * crate);              \
                f_[4] = (__bf16)(wb_.x * rate + cb_.x * crate);              \
                f_[5] = (__bf16)(wb_.y * rate + cb_.y * crate);              \
                f_[6] = (__bf16)(wb_.z * rate + cb_.z * crate);              \
                f_[7] = (__bf16)(wb_.w * rate + cb_.w * crate);              \
            } else {                                                         \
                f_ = (bf16x8)0;                                              \
            }                                                                \
            *(bf16x8*)((base) + awr[i2]) = f_;                               \
        }                                                                    \
    }

#define LOAD_REGS(ko)                                                        \
    {                                                                        \
        if (val) {                                                           \
            _Pragma("unroll") for (int i = 0; i < 8; ++i) {                  \
                cc[i] = *(const float4*)(cptr + (ko) + i * 4);               \
                uc[i] = *(const float4*)(wptr + (ko) + i * 4);               \
            }                                                                \
        }                                                                    \
        _Pragma("unroll") for (int p = 0; p < 5; ++p)                        \
            wreg[p] = *(const bf16x8*)(wsrc[p] + (ko));                      \
    }

    // ---- prologue: stage chunk 0 directly; prefetch chunk 1 into regs ----
    {
        LOAD_REGS(0);
        COMMIT_A(smem + ABUF(0));
#pragma unroll
        for (int p = 0; p < 5; ++p) *(bf16x8*)(smem + WBUF(0) + wwr[p]) = wreg[p];
        LOAD_REGS(CHK);
    }
    __syncthreads();

    // ---- main loop: 8 phases ----
    for (int ch = 0; ch < NCH; ++ch) {
        // 1) commit prefetched chunk ch+1 to the other buffer
        if (ch + 1 < NCH) {
            char* An = smem + ABUF((ch + 1) & 1);
            char* Wn = smem + WBUF((ch + 1) & 1);
            COMMIT_A(An);
#pragma unroll
            for (int p = 0; p < 5; ++p) *(bf16x8*)(Wn + wwr[p]) = wreg[p];
        }
        // 2) issue global loads for chunk ch+2 (held in regs across compute)
        if (ch + 2 < NCH) {
            const int ko = (ch + 2) * CHK;
            LOAD_REGS(ko);
        }
        // 3) compute chunk ch: 4 sub-k x 5 nt = 20 MFMA
        const char* Ab = smem + ABUF(ch & 1);
        const char* Wb = smem + WBUF(ch & 1);
#pragma unroll
        for (int s = 0; s < 4; ++s) {
            bf16x8 a = *(const bf16x8*)(Ab + aoff[s]);
#pragma unroll
            for (int nt = 0; nt < 5; ++nt) {
                bf16x8 bw = *(const bf16x8*)(Wb + woff[s][nt]);
                acc[nt] = __builtin_amdgcn_mfma_f32_16x16x32_bf16(a, bw, acc[nt], 0, 0, 0);
            }
        }
        __syncthreads();
    }

    // ---- epilogue: C/D col = lane&15, row = (lane>>4)*4 + reg  [verified R2-R16] ----
    const int orow = rowbase + wv * 16 + kgrp * 4;
#pragma unroll
    for (int nt = 0; nt < 5; ++nt) {
        const int col = nt * 16 + l15;
        if (col < NTAGS) {
            const float bias = b_out[col];
#pragma unroll
            for (int i = 0; i < 4; ++i) {
                out[(size_t)(orow + i) * NTAGS + col] = acc[nt][i] + bias;
            }
        }
    }
#undef COMMIT_A
#undef LOAD_REGS
}

extern "C" void kernel_launch(void* const* d_in, const int* in_sizes, int n_in,
                              void* d_out, int out_size, void* d_ws, size_t ws_size,
                              hipStream_t stream) {
    const float* out_char = (const float*)d_in[0];
    const float* out_word = (const float*)d_in[1];
    const int* word_idx = (const int*)d_in[2];
    const int* is_head = (const int*)d_in[3];
    const int* valid_mask = (const int*)d_in[4];
    const float* W_out = (const float*)d_in[5];
    const float* b_out = (const float*)d_in[6];
    float* out = (float*)d_out;
    __bf16* Wt = (__bf16*)d_ws;  // 80*1024*2 = 160 KB

    prep_w_kernel<<<HH / 64, 256, 0, stream>>>(W_out, Wt);

    const int rows = 16 * TT;  // B*T = 32768
    slu_main<<<rows / MROWS, THREADS, LDS_BYTES, stream>>>(out_char, out_word, word_idx,
                                                           is_head, valid_mask, Wt, b_out,
                                                           out);
}

// Round 18
// 35.149 us; speedup vs baseline: 1.4290x; 1.4290x over previous
//
#include <hip/hip_runtime.h>
#include <hip/hip_bf16.h>

#define TT 2048
#define HH 1024
#define NTAGS 74
#define NPAD 80
#define CHK 64            // K elements per chunk
#define NCH (HH / CHK)    // 16 chunks
#define MROWS 64          // rows per block
#define THREADS 256
#define NXCD 8

typedef __bf16 bf16x8 __attribute__((ext_vector_type(8)));
typedef float f32x4 __attribute__((ext_vector_type(4)));

// Transpose + convert W_out [1024][74] f32 -> Wt [80][1024] bf16 (pad cols 74..79 = 0)
__global__ __launch_bounds__(256) void prep_w_kernel(const float* __restrict__ W,
                                                     __bf16* __restrict__ Wt) {
    __shared__ float tile[64][80];
    const int k0 = blockIdx.x * 64;
    const int tid = threadIdx.x;
    for (int i = tid; i < 64 * NTAGS; i += 256) {
        int k = i / NTAGS, n = i - k * NTAGS;
        tile[k][n] = W[(k0 + k) * NTAGS + n];
    }
    __syncthreads();
    for (int i = tid; i < NPAD * 64; i += 256) {
        int n = i >> 6, kk = i & 63;
        float v = (n < NTAGS) ? tile[kk][n] : 0.0f;
        Wt[n * HH + k0 + kk] = (__bf16)v;
    }
}

// R18 = R12 verbatim (best measured: 35.05 us). 16-phase double/triple-buffered
// LDS pipeline, M=64 rows/block, grid 512 (2 blocks/CU), XCD-aware bijective
// block swizzle. Phase-granularity curve is convex around 16 (32->37-47us,
// 8->50us); 15 orthogonal probes (occupancy, coalescing, MLP, async staging,
// TLP, XCD locality, barrier semantics, work deletion, dedup) all null at
// 35+-0.5us => kernel sits at the tiered-memory service floor:
// ~134MB char + ~40MB unique word + ~40MB W + 10MB out ~= 28-30us service
// + prep_w/launch ~= 3-5us.
__global__ __launch_bounds__(256, 2) void slu_main(const float* __restrict__ out_char,
                                                   const float* __restrict__ out_word,
                                                   const int* __restrict__ word_idx,
                                                   const int* __restrict__ is_head,
                                                   const int* __restrict__ valid_mask,
                                                   const __bf16* __restrict__ Wt,
                                                   const float* __restrict__ b_out,
                                                   float* __restrict__ out) {
    // LDS: A[3] @ 0 (3*8192), W[2] @ 24576 (2*10240) = 45056 B
    __shared__ __align__(16) char smem[45056];
    const int tid = threadIdx.x;
    const int wv = tid >> 6;
    const int lane = tid & 63;
    const int l15 = lane & 15;
    const int kgrp = lane >> 4;

    // ---- XCD-aware bijective swizzle (512 blocks = 8 XCDs x 64 chunks) ----
    const int bid = blockIdx.x;
    const int rb = (bid & (NXCD - 1)) * (512 / NXCD) + (bid >> 3);
    const int rowbase = rb * MROWS;

    // ---- A staging (R5 map): thread covers row rloc=(tid>>2), k-sub q=(tid&3) ----
    const int rloc = tid >> 2;
    const int q = tid & 3;
    const int r = rowbase + rloc;
    const int bq = r >> 11;  // T = 2048
    const int widx = word_idx[r];
    const int val = valid_mask[r];
    const float rt = is_head[r] ? 0.88f : 0.70f;
    const float rate = val ? rt : 0.0f;
    const float crate = val ? (1.0f - rt) : 0.0f;
    const float* cptr = out_char + (size_t)r * HH + q * 16;
    const float* wptr = out_word + ((size_t)bq * TT + widx) * HH + q * 16;
    const int asw = (rloc & 7) << 4;
    const int awr0 = (rloc * 128 + q * 32) ^ asw;
    const int awr1 = (rloc * 128 + q * 32 + 16) ^ asw;

    // ---- W staging (R5 map): 640 16B-units/chunk; thread covers tid, tid+256, (tid<128)?tid+512 ----
    const int wn0 = tid >> 3, wsb = tid & 7;
    const __bf16* wgp0 = Wt + (size_t)wn0 * HH + wsb * 8;
    const __bf16* wgp1 = wgp0 + 32 * HH;
    const __bf16* wgp2 = wgp0 + 64 * HH;
    const int wsw = (wn0 & 7) << 4;
    const int wwr0 = (wn0 * 128 + wsb * 16) ^ wsw;
    const int wwr1 = ((wn0 + 32) * 128 + wsb * 16) ^ wsw;
    const int wwr2 = ((wn0 + 64) * 128 + wsb * 16) ^ wsw;
    const bool w3 = (tid < 128);

    // ---- fragment read offsets (swizzle matches writes; row&7 == l15&7 for A and W) ----
    const int fsw = (l15 & 7) << 4;
    const int arow = wv * 16 + l15;
    int aoff[2], woff[2][5];
#pragma unroll
    for (int s = 0; s < 2; ++s) {
        aoff[s] = (arow * 128 + s * 64 + kgrp * 16) ^ fsw;
#pragma unroll
        for (int nt = 0; nt < 5; ++nt)
            woff[s][nt] = ((nt * 16 + l15) * 128 + s * 64 + kgrp * 16) ^ fsw;
    }

    f32x4 acc[5];
#pragma unroll
    for (int nt = 0; nt < 5; ++nt) acc[nt] = (f32x4){0.f, 0.f, 0.f, 0.f};

    float4 ac[4], aw[4];   // held A loads (chunk ch+2)
    bf16x8 wreg0, wreg1, wreg2;

    // ---- prologue: stage chunk 0 directly; prefetch chunk 1 into regs ----
    {
        float4 c0[4], w0[4];
        if (val) {
#pragma unroll
            for (int i = 0; i < 4; ++i) {
                c0[i] = *(const float4*)(cptr + i * 4);
                w0[i] = *(const float4*)(wptr + i * 4);
            }
        }
        bf16x8 wr0 = *(const bf16x8*)(wgp0);
        bf16x8 wr1 = *(const bf16x8*)(wgp1);
        bf16x8 wr2 = w3 ? *(const bf16x8*)(wgp2) : (bf16x8)0;
        bf16x8 f0, f1;
        if (val) {
#pragma unroll
            for (int i = 0; i < 2; ++i) {
                f0[i * 4 + 0] = (__bf16)(w0[i].x * rate + c0[i].x * crate);
                f0[i * 4 + 1] = (__bf16)(w0[i].y * rate + c0[i].y * crate);
                f0[i * 4 + 2] = (__bf16)(w0[i].z * rate + c0[i].z * crate);
                f0[i * 4 + 3] = (__bf16)(w0[i].w * rate + c0[i].w * crate);
                f1[i * 4 + 0] = (__bf16)(w0[i + 2].x * rate + c0[i + 2].x * crate);
                f1[i * 4 + 1] = (__bf16)(w0[i + 2].y * rate + c0[i + 2].y * crate);
                f1[i * 4 + 2] = (__bf16)(w0[i + 2].z * rate + c0[i + 2].z * crate);
                f1[i * 4 + 3] = (__bf16)(w0[i + 2].w * rate + c0[i + 2].w * crate);
            }
        } else {
            f0 = (bf16x8)0; f1 = (bf16x8)0;
        }
        *(bf16x8*)(smem + awr0) = f0;
        *(bf16x8*)(smem + awr1) = f1;
        *(bf16x8*)(smem + 24576 + wwr0) = wr0;
        *(bf16x8*)(smem + 24576 + wwr1) = wr1;
        if (w3) *(bf16x8*)(smem + 24576 + wwr2) = wr2;
        // prefetch chunk 1 into regs
        if (val) {
#pragma unroll
            for (int i = 0; i < 4; ++i) {
                ac[i] = *(const float4*)(cptr + CHK + i * 4);
                aw[i] = *(const float4*)(wptr + CHK + i * 4);
            }
        }
        wreg0 = *(const bf16x8*)(wgp0 + CHK);
        wreg1 = *(const bf16x8*)(wgp1 + CHK);
        wreg2 = w3 ? *(const bf16x8*)(wgp2 + CHK) : (bf16x8)0;
    }
    __syncthreads();

    // ---- main loop ----
    for (int ch = 0; ch < NCH; ++ch) {
        // 1) commit prefetched chunk ch+1 to LDS
        if (ch + 1 < NCH) {
            char* An = smem + ((ch + 1) % 3) * 8192;
            char* Wn = smem + 24576 + ((ch + 1) & 1) * 10240;
            bf16x8 f0, f1;
            if (val) {
#pragma unroll
                for (int i = 0; i < 2; ++i) {
                    f0[i * 4 + 0] = (__bf16)(aw[i].x * rate + ac[i].x * crate);
                    f0[i * 4 + 1] = (__bf16)(aw[i].y * rate + ac[i].y * crate);
                    f0[i * 4 + 2] = (__bf16)(aw[i].z * rate + ac[i].z * crate);
                    f0[i * 4 + 3] = (__bf16)(aw[i].w * rate + ac[i].w * crate);
                    f1[i * 4 + 0] = (__bf16)(aw[i + 2].x * rate + ac[i + 2].x * crate);
                    f1[i * 4 + 1] = (__bf16)(aw[i + 2].y * rate + ac[i + 2].y * crate);
                    f1[i * 4 + 2] = (__bf16)(aw[i + 2].z * rate + ac[i + 2].z * crate);
                    f1[i * 4 + 3] = (__bf16)(aw[i + 2].w * rate + ac[i + 2].w * crate);
                }
            } else {
                f0 = (bf16x8)0; f1 = (bf16x8)0;
            }
            *(bf16x8*)(An + awr0) = f0;
            *(bf16x8*)(An + awr1) = f1;
            *(bf16x8*)(Wn + wwr0) = wreg0;
            *(bf16x8*)(Wn + wwr1) = wreg1;
            if (w3) *(bf16x8*)(Wn + wwr2) = wreg2;
        }
        // 2) issue global loads for chunk ch+2 (held in regs across compute)
        if (ch + 2 < NCH) {
            const int ko = (ch + 2) * CHK;
            if (val) {
#pragma unroll
                for (int i = 0; i < 4; ++i) {
                    ac[i] = *(const float4*)(cptr + ko + i * 4);
                    aw[i] = *(const float4*)(wptr + ko + i * 4);
                }
            }
            wreg0 = *(const bf16x8*)(wgp0 + ko);
            wreg1 = *(const bf16x8*)(wgp1 + ko);
            wreg2 = w3 ? *(const bf16x8*)(wgp2 + ko) : (bf16x8)0;
        }
        // 3) compute chunk ch
        const char* Ab = smem + (ch % 3) * 8192;
        const char* Wb = smem + 24576 + (ch & 1) * 10240;
#pragma unroll
        for (int s = 0; s < 2; ++s) {
            bf16x8 a = *(const bf16x8*)(Ab + aoff[s]);
#pragma unroll
            for (int nt = 0; nt < 5; ++nt) {
                bf16x8 bw = *(const bf16x8*)(Wb + woff[s][nt]);
                acc[nt] = __builtin_amdgcn_mfma_f32_16x16x32_bf16(a, bw, acc[nt], 0, 0, 0);
            }
        }
        __syncthreads();
    }

    // ---- epilogue: C/D col = lane&15, row = (lane>>4)*4 + reg  [verified R2-R17] ----
    const int orow = rowbase + wv * 16 + kgrp * 4;
#pragma unroll
    for (int nt = 0; nt < 5; ++nt) {
        const int col = nt * 16 + l15;
        if (col < NTAGS) {
            const float bias = b_out[col];
#pragma unroll
            for (int i = 0; i < 4; ++i) {
                out[(size_t)(orow + i) * NTAGS + col] = acc[nt][i] + bias;
            }
        }
    }
}

extern "C" void kernel_launch(void* const* d_in, const int* in_sizes, int n_in,
                              void* d_out, int out_size, void* d_ws, size_t ws_size,
                              hipStream_t stream) {
    const float* out_char = (const float*)d_in[0];
    const float* out_word = (const float*)d_in[1];
    const int* word_idx = (const int*)d_in[2];
    const int* is_head = (const int*)d_in[3];
    const int* valid_mask = (const int*)d_in[4];
    const float* W_out = (const float*)d_in[5];
    const float* b_out = (const float*)d_in[6];
    float* out = (float*)d_out;
    __bf16* Wt = (__bf16*)d_ws;  // 80*1024*2 = 160 KB

    prep_w_kernel<<<HH / 64, 256, 0, stream>>>(W_out, Wt);

    const int rows = 16 * TT;  // B*T = 32768
    slu_main<<<rows / MROWS, THREADS, 0, stream>>>(out_char, out_word, word_idx, is_head,
                                                   valid_mask, Wt, b_out, out);
}